// Round 6
// baseline (257.292 us; speedup 1.0000x reference)
//
#include <hip/hip_runtime.h>

// Problem constants
#define BB 256      // batch
#define CCH 512     // channels
#define HW 196      // 14*14 spatial
#define TT 197      // templates_b rows (196 + 1 negative)
#define TROWS 208   // padded T rows (13 * 16)
#define TBK 224     // padded K for templates (7 * 32)
#define CST (CCH * TROWS)   // colp per-g stride

typedef __attribute__((ext_vector_type(8))) short bf16x8;
typedef __attribute__((ext_vector_type(4))) float f32x4;

__device__ __forceinline__ unsigned short f2bf(float f) {
    union { float f; unsigned u; } v; v.f = f;
    unsigned r = v.u + 0x7FFFu + ((v.u >> 16) & 1u);   // round-to-nearest-even
    return (unsigned short)(r >> 16);
}

// ---- prep: wgs 0..181 convert templates_b*tau -> bf16 zero-padded 208x224;
// wg 182: gmax = max(templates_f) (center peak is in every 14x14 window, so
// max(sel) == max(templates_f)) + zero-padded pT copy.
__global__ void prep(const float* __restrict__ tf, const float* __restrict__ tb,
                     const float* __restrict__ pT,
                     float* __restrict__ wsf, unsigned short* __restrict__ tb_bf,
                     float* __restrict__ pT_pad) {
    if (blockIdx.x < 182) {
        int i = blockIdx.x * 256 + threadIdx.x;     // 182*256 == 208*224 exactly
        int r = i / TBK, k = i % TBK;
        const float tau = 0.5f / 196.0f;
        float v = (r < TT && k < HW) ? tb[r * HW + k] * tau : 0.0f;
        tb_bf[i] = f2bf(v);
    } else {
        if (threadIdx.x < TROWS)
            pT_pad[threadIdx.x] = (threadIdx.x < TT) ? pT[threadIdx.x] : 0.0f;
        __shared__ float red[256];
        float m = -1e30f;
        for (int i = threadIdx.x; i < HW * HW; i += 256) m = fmaxf(m, tf[i]);
        red[threadIdx.x] = m;
        __syncthreads();
        for (int s = 128; s > 0; s >>= 1) {
            if (threadIdx.x < s) red[threadIdx.x] = fmaxf(red[threadIdx.x], red[threadIdx.x + s]);
            __syncthreads();
        }
        if (threadIdx.x == 0) wsf[0] = red[0];
    }
}

// ---- K1: wg (c, g) = 64 batches of one channel, 4 independent waves.
// Lane (l15,lg) of wave w owns row b = g*64+w*16+l15, chunks kt*8+2lg+{0,1}
// == the mfma_16x16x32 B-frag layout. stream -> argmax -> mask/stores -> GEMM
// -> exp col-partials over 16 b (shfl over l15) -> 4-wave LDS fold -> colp.
extern "C" __global__ __launch_bounds__(256, 4)
void k1_mask_gemm(const float* __restrict__ x, const float* __restrict__ tf,
                  const unsigned short* __restrict__ tb_bf, const float* __restrict__ wsf,
                  float* __restrict__ xm_out, float* __restrict__ mask_out,
                  float* __restrict__ colp)
{
    __shared__ float s_col[4][TROWS];
    const int tid  = threadIdx.x;
    const int lane = tid & 63;
    const int w    = tid >> 6;
    const int l15  = lane & 15, lg = lane >> 4;
    const int c    = blockIdx.x >> 2, g = blockIdx.x & 3;
    const float rg = 1.0f / wsf[0];

    const int b = g * 64 + w * 16 + l15;
    const size_t rowoff = ((size_t)b * CCH + c) * HW;
    const float* xrow = x + rowoff;

    // ---- load this lane's 12 (13 for lg==0) chunks of its row
    f32x4 u[13];
    #pragma unroll
    for (int kt = 0; kt < 6; ++kt) {
        u[2 * kt]     = *(const f32x4*)(xrow + kt * 32 + lg * 8);
        u[2 * kt + 1] = *(const f32x4*)(xrow + kt * 32 + lg * 8 + 4);
    }
    if (lg == 0) u[12] = *(const f32x4*)(xrow + 192);
    else         u[12] = (f32x4){-__builtin_inff(), -__builtin_inff(),
                                 -__builtin_inff(), -__builtin_inff()};

    // ---- argmax (k ascends within each lane's scan -> strict > keeps first)
    float bv = -__builtin_inff(); int bi = 0;
    #pragma unroll
    for (int j = 0; j < 13; ++j) {
        const int k0 = (j < 12) ? (((j >> 1) * 8 + lg * 2 + (j & 1)) * 4) : 192;
        #pragma unroll
        for (int e = 0; e < 4; ++e) {
            float v = u[j][e];
            if (v > bv) { bv = v; bi = k0 + e; }
        }
    }
    #pragma unroll
    for (int m = 16; m <= 32; m <<= 1) {   // reduce over lg
        float ov = __shfl_xor(bv, m, 64);
        int   oi = __shfl_xor(bi, m, 64);
        if (ov > bv || (ov == bv && oi < bi)) { bv = ov; bi = oi; }
    }

    // ---- mask, outputs, B-frag pack (u dies into fr)
    const float* selrow = tf + (size_t)bi * HW;
    float* xmrow = xm_out + rowoff;
    float* mkrow = mask_out + rowoff;
    bf16x8 fr[7];

    #pragma unroll
    for (int kt = 0; kt < 6; ++kt) {
        #pragma unroll
        for (int h = 0; h < 2; ++h) {
            const int k0 = kt * 32 + lg * 8 + h * 4;
            f32x4 sel = *(const f32x4*)(selrow + k0);
            f32x4 mk, xm;
            #pragma unroll
            for (int e = 0; e < 4; ++e) {
                float m = fmaxf(sel[e] * rg - 0.2f, 0.0f) * 5.0f;
                mk[e] = m;
                xm[e] = u[2 * kt + h][e] * m;
            }
            *(f32x4*)(xmrow + k0) = xm;
            *(f32x4*)(mkrow + k0) = mk;
            #pragma unroll
            for (int e = 0; e < 4; ++e) fr[kt][h * 4 + e] = (short)f2bf(xm[e]);
        }
    }
    {   // kt=6: only lg==0 has real data (floats 192..195)
        fr[6] = (bf16x8){0, 0, 0, 0, 0, 0, 0, 0};
        if (lg == 0) {
            f32x4 sel = *(const f32x4*)(selrow + 192);
            f32x4 mk, xm;
            #pragma unroll
            for (int e = 0; e < 4; ++e) {
                float m = fmaxf(sel[e] * rg - 0.2f, 0.0f) * 5.0f;
                mk[e] = m;
                xm[e] = u[12][e] * m;
            }
            *(f32x4*)(xmrow + 192) = xm;
            *(f32x4*)(mkrow + 192) = mk;
            #pragma unroll
            for (int e = 0; e < 4; ++e) fr[6][e] = (short)f2bf(xm[e]);
        }
    }

    // ---- GEMM: tr[t = mt*16+lg*4+e][b], A-frags from L2
    f32x4 acc[13];
    #pragma unroll
    for (int mt = 0; mt < 13; ++mt) acc[mt] = (f32x4){0.f, 0.f, 0.f, 0.f};
    #pragma unroll
    for (int kt = 0; kt < 7; ++kt) {
        const int kb = kt * 32 + lg * 8;
        const bf16x8 bfrag = fr[kt];
        #pragma unroll
        for (int mt = 0; mt < 13; ++mt) {
            bf16x8 afrag = *(const bf16x8*)(tb_bf + (mt * 16 + l15) * TBK + kb);
            acc[mt] = __builtin_amdgcn_mfma_f32_16x16x32_bf16(afrag, bfrag, acc[mt], 0, 0, 0);
        }
    }

    // ---- exp col-partials over this wave's 16 b, fold 4 waves, write colp
    #pragma unroll
    for (int mt = 0; mt < 13; ++mt) {
        f32x4 s;
        #pragma unroll
        for (int e = 0; e < 4; ++e) s[e] = __expf(acc[mt][e]);
        #pragma unroll
        for (int m = 1; m <= 8; m <<= 1) {
            #pragma unroll
            for (int e = 0; e < 4; ++e) s[e] += __shfl_xor(s[e], m, 64);
        }
        if (l15 == 0) *(f32x4*)(&s_col[w][mt * 16 + lg * 4]) = s;
    }
    __syncthreads();
    if (tid < TROWS) {
        float s = s_col[0][tid] + s_col[1][tid] + s_col[2][tid] + s_col[3][tid];
        colp[(size_t)g * CST + c * TROWS + tid] = s;
    }
}

// ---- K2: recompute the GEMM bitwise-identically from xm (read from d_out),
// sum the 4 colp partials -> rA, then px / loss fully in-register.
extern "C" __global__ __launch_bounds__(256, 4)
void k2_loss(const float* __restrict__ xm, const unsigned short* __restrict__ tb_bf,
             const float* __restrict__ pT_pad, const float* __restrict__ colp,
             float* __restrict__ loss_part)
{
    __shared__ float red[4];
    const int tid  = threadIdx.x;
    const int lane = tid & 63;
    const int w    = tid >> 6;
    const int l15  = lane & 15, lg = lane >> 4;
    const int c    = blockIdx.x >> 2, g = blockIdx.x & 3;

    const int b = g * 64 + w * 16 + l15;
    const float* xrow = xm + ((size_t)b * CCH + c) * HW;

    // ---- B-frag pack straight from xm (no retention)
    bf16x8 fr[7];
    #pragma unroll
    for (int kt = 0; kt < 6; ++kt) {
        f32x4 u0 = *(const f32x4*)(xrow + kt * 32 + lg * 8);
        f32x4 u1 = *(const f32x4*)(xrow + kt * 32 + lg * 8 + 4);
        #pragma unroll
        for (int e = 0; e < 4; ++e) {
            fr[kt][e]     = (short)f2bf(u0[e]);
            fr[kt][e + 4] = (short)f2bf(u1[e]);
        }
    }
    fr[6] = (bf16x8){0, 0, 0, 0, 0, 0, 0, 0};
    if (lg == 0) {
        f32x4 u0 = *(const f32x4*)(xrow + 192);
        #pragma unroll
        for (int e = 0; e < 4; ++e) fr[6][e] = (short)f2bf(u0[e]);
    }

    // ---- identical GEMM -> bitwise same acc as K1
    f32x4 acc[13];
    #pragma unroll
    for (int mt = 0; mt < 13; ++mt) acc[mt] = (f32x4){0.f, 0.f, 0.f, 0.f};
    #pragma unroll
    for (int kt = 0; kt < 7; ++kt) {
        const int kb = kt * 32 + lg * 8;
        const bf16x8 bfrag = fr[kt];
        #pragma unroll
        for (int mt = 0; mt < 13; ++mt) {
            bf16x8 afrag = *(const bf16x8*)(tb_bf + (mt * 16 + l15) * TBK + kb);
            acc[mt] = __builtin_amdgcn_mfma_f32_16x16x32_bf16(afrag, bfrag, acc[mt], 0, 0, 0);
        }
    }

    // ---- Phase B: A = sum_g colp, p = exp*1/A, px = sum_t pT*p
    const float* cpc = colp + (size_t)c * TROWS;
    float px = 0.f;
    #pragma unroll
    for (int mt = 0; mt < 13; ++mt) {
        const int t0 = mt * 16 + lg * 4;
        f32x4 a0 = *(const f32x4*)(cpc + 0 * CST + t0);
        f32x4 a1 = *(const f32x4*)(cpc + 1 * CST + t0);
        f32x4 a2 = *(const f32x4*)(cpc + 2 * CST + t0);
        f32x4 a3 = *(const f32x4*)(cpc + 3 * CST + t0);
        f32x4 pt = *(const f32x4*)(pT_pad + t0);
        #pragma unroll
        for (int e = 0; e < 4; ++e) {
            float p = __expf(acc[mt][e]) / (a0[e] + a1[e] + a2[e] + a3[e]);
            acc[mt][e] = p;
            px += pt[e] * p;
        }
    }
    px += __shfl_xor(px, 16, 64);
    px += __shfl_xor(px, 32, 64);
    const float rpx = 1.0f / px;

    // ---- Phase C: part = sum pT * p * log(p/px); reduce over all 64 lanes
    float part = 0.f;
    #pragma unroll
    for (int mt = 0; mt < 13; ++mt) {
        const int t0 = mt * 16 + lg * 4;
        f32x4 pt = *(const f32x4*)(pT_pad + t0);
        #pragma unroll
        for (int e = 0; e < 4; ++e)
            part += pt[e] * acc[mt][e] * __logf(acc[mt][e] * rpx);
    }
    #pragma unroll
    for (int off = 1; off <= 32; off <<= 1) part += __shfl_xor(part, off, 64);
    if (lane == 0) red[w] = part;
    __syncthreads();
    if (tid == 0) loss_part[(size_t)c * 4 + g] = red[0] + red[1] + red[2] + red[3];
}

// ---- K3: fold 4 wg-partials per channel
__global__ void k3_finish(const float* __restrict__ lp, float* __restrict__ loss_out) {
    int c = blockIdx.x * 256 + threadIdx.x;
    if (c < CCH)
        loss_out[c] = -(lp[4 * c] + lp[4 * c + 1] + lp[4 * c + 2] + lp[4 * c + 3]);
}

extern "C" void kernel_launch(void* const* d_in, const int* in_sizes, int n_in,
                              void* d_out, int out_size, void* d_ws, size_t ws_size,
                              hipStream_t stream) {
    const float* x  = (const float*)d_in[0];
    const float* tf = (const float*)d_in[1];
    const float* tb = (const float*)d_in[2];
    const float* pT = (const float*)d_in[3];

    const size_t NOUT = (size_t)BB * CCH * HW;
    float* xm_out = (float*)d_out;
    float* mk_out = xm_out + NOUT;
    float* ls_out = mk_out + NOUT;

    // ws layout (all 64B-aligned): wsf | tb_bf | pT_pad | colp | loss_part
    char* wsp = (char*)d_ws;
    float*          wsf    = (float*)wsp;                         // 4 B
    unsigned short* tb_bf  = (unsigned short*)(wsp + 64);         // 93184 B
    float*          pT_pad = (float*)(wsp + 93248);               // 832 B
    float*          colp   = (float*)(wsp + 94080);               // 4*512*208*4 = 1703936 B
    float*          lpart  = (float*)(wsp + 1798016);             // 8192 B

    prep<<<183, 256, 0, stream>>>(tf, tb, pT, wsf, tb_bf, pT_pad);
    k1_mask_gemm<<<2048, 256, 0, stream>>>(x, tf, tb_bf, wsf, xm_out, mk_out, colp);
    k2_loss<<<2048, 256, 0, stream>>>(xm_out, tb_bf, pT_pad, colp, lpart);
    k3_finish<<<2, 256, 0, stream>>>(lpart, ls_out);
}